// Round 2
// baseline (604.177 us; speedup 1.0000x reference)
//
#include <hip/hip_runtime.h>

// VQ-VAE quantizer: z [16,4096,64] f32, embedding [1024,64] f32.
// Outputs concatenated in d_out (float32): [0]=loss, [1..4194304]=z_q,
// [4194305..]=argmin indices (as float).
//
// Correctness-critical (verified absmax 0.0 previously): argmin mirrors numpy
// bitwise. d = fmaf(-2,dot,(zz+ee)); zz/ee use numpy's pairwise 8-accumulator
// tree with fp-contract OFF; strict < gives first-index tie-break; segments
// merged in ascending order. Loss: wave0 per-row sequential col sum + 64-lane
// shfl tree + one atomic/block (identical structure to verified kernel).
//
// R4 change: break the scalar-load serialization of the e-row stream.
// Evidence: R0 (LDS-staged z) and R1 (register z) both landed at ~210us with
// VALUBusy ~38% and VGPR<=64 -> the common bottleneck is the wave-uniform
// emb read, which LLVM promotes to s_load (e-row -> 64 SGPRs; SGPR file
// ~102/wave caps pipelining at <2 codes; scalar-cache thrash -> ~300cyc
// stall per code vs 142cyc compute = 38% VALUBusy. Matches both rounds.)
// Fix: taint the emb address with an opaque zero VGPR so the loads must take
// the vector path (vmcnt-counted, pipelined across the unroll-2 codes, data
// in VGPRs). zr(64) + 2x16 e-floats + accs ~= 110 VGPR, fits (512,4)'s 128.

#define D 64
#define NE 1024
#define SEGS 8
#define CPS 128              // codes per segment = NE/SEGS
#define ROWS 64              // rows per block
#define TPB 512

__global__ __launch_bounds__(TPB, 4) void vq_kernel(const float* __restrict__ z,
                                                    const float* __restrict__ emb,
                                                    float* __restrict__ out_loss,
                                                    float* __restrict__ out_zq,
                                                    float* __restrict__ out_idx,
                                                    float loss_scale) {
    __shared__ float ee_lds[NE];
    __shared__ float smv[SEGS * ROWS];
    __shared__ int   smi[SEGS * ROWS];

    const int tid = threadIdx.x;
    const size_t blockRow = (size_t)blockIdx.x * ROWS;
    const int rrow = tid & (ROWS - 1);   // row within tile (same mapping in every wave)
    const int seg  = tid >> 6;           // wave id = codebook segment (0..7)

    // --- ee[j] = numpy-pairwise sum(e*e) for all 1024 codes (2 per thread).
    //     Must match np bitwise: 8 accumulators over stride-8 cols, contract off.
    {
#pragma clang fp contract(off)
#pragma unroll
        for (int cc = 0; cc < 2; ++cc) {
            const int j = tid + cc * TPB;
            const float4* e4 = (const float4*)(emb + ((size_t)j << 6));
            float4 a = e4[0], b = e4[1];
            float r[8];
            r[0] = a.x*a.x; r[1] = a.y*a.y; r[2] = a.z*a.z; r[3] = a.w*a.w;
            r[4] = b.x*b.x; r[5] = b.y*b.y; r[6] = b.z*b.z; r[7] = b.w*b.w;
#pragma unroll
            for (int g = 1; g < 8; ++g) {
                float4 c = e4[2*g], e = e4[2*g + 1];
                r[0] = r[0] + c.x*c.x; r[1] = r[1] + c.y*c.y;
                r[2] = r[2] + c.z*c.z; r[3] = r[3] + c.w*c.w;
                r[4] = r[4] + e.x*e.x; r[5] = r[5] + e.y*e.y;
                r[6] = r[6] + e.z*e.z; r[7] = r[7] + e.w*e.w;
            }
            ee_lds[j] = ((r[0]+r[1]) + (r[2]+r[3])) + ((r[4]+r[5]) + (r[6]+r[7]));
        }
    }

    // --- z row straight into registers (per-lane row; every wave loads the
    //     same 64-row tile, lane r <-> row r). z is read once from HBM; the
    //     256B-stride lane pattern is absorbed by L1/L2 across the 16 loads.
    float zr[D];
    {
        const float4* zrow4 = (const float4*)(z + (blockRow + rrow) * D);
#pragma unroll
        for (int c = 0; c < 16; ++c) {
            float4 v = zrow4[c];
            zr[4*c+0] = v.x; zr[4*c+1] = v.y; zr[4*c+2] = v.z; zr[4*c+3] = v.w;
        }
    }

    // zz = numpy-pairwise sum(z*z), contract off.
    float zz;
    {
#pragma clang fp contract(off)
        float r[8];
#pragma unroll
        for (int jj = 0; jj < 8; ++jj) { float t = zr[jj] * zr[jj]; r[jj] = t; }
#pragma unroll
        for (int i = 8; i < 64; i += 8) {
#pragma unroll
            for (int jj = 0; jj < 8; ++jj) { float t = zr[i+jj] * zr[i+jj]; r[jj] = r[jj] + t; }
        }
        zz = ((r[0]+r[1]) + (r[2]+r[3])) + ((r[4]+r[5]) + (r[6]+r[7]));
    }

    __syncthreads();   // ee_lds ready

    // Opaque zero in a VGPR: the compiler cannot prove it is 0 or uniform, so
    // emb addresses tainted with it MUST use vector-memory loads (VMEM path,
    // vmcnt-counted, pipelined) instead of being promoted to s_load chains.
    int vz;
    asm("v_mov_b32 %0, 0" : "=v"(vz));

    // --- Scan this wave's codebook segment. ---
    float minv = __builtin_inff();
    int mini = 0;
    const int jbase = __builtin_amdgcn_readfirstlane(seg * CPS);
#pragma unroll 2
    for (int jj = 0; jj < CPS; ++jj) {
        const int j = jbase + jj;
        const float4* ew4 = (const float4*)(emb + ((size_t)j << 6)) + vz;  // VMEM-forced
        float p0 = 0.f, p1 = 0.f, p2 = 0.f, p3 = 0.f;
#pragma unroll
        for (int c = 0; c < 16; ++c) {
            float4 e4 = ew4[c];
            p0 = fmaf(zr[4*c+0], e4.x, p0);
            p1 = fmaf(zr[4*c+1], e4.y, p1);
            p2 = fmaf(zr[4*c+2], e4.z, p2);
            p3 = fmaf(zr[4*c+3], e4.w, p3);
        }
        float dot = (p0 + p1) + (p2 + p3);
        float t1 = zz + ee_lds[j];             // mirrors np (zz + ee) rounding
        float d = fmaf(-2.0f, dot, t1);        // == round(t1 - 2*dot)
        if (d < minv) { minv = d; mini = j; }  // strict < -> first index on tie
    }

    smv[seg * ROWS + rrow] = minv;
    smi[seg * ROWS + rrow] = mini;
    __syncthreads();

    // --- Epilogue: every wave redundantly merges row rrow (identical result),
    //     then wave `seg` stores columns [8*seg, 8*seg+8) of z_q. ---
    float best = __builtin_inff();
    int bi = 0;
#pragma unroll
    for (int s = 0; s < SEGS; ++s) {           // ascending seg = ascending j
        float v = smv[s * ROWS + rrow];
        if (v < best) { best = v; bi = smi[s * ROWS + rrow]; }
    }

    const float4* qe4 = (const float4*)(emb + ((size_t)bi << 6));
    float s = 0.f;
    float* orow = out_zq + (blockRow + rrow) * D;
#pragma unroll
    for (int c = 0; c < 16; ++c) {
        float4 q = qe4[c];
        float z0 = zr[4*c+0], z1 = zr[4*c+1], z2 = zr[4*c+2], z3 = zr[4*c+3];
        float d0 = q.x - z0, d1 = q.y - z1, d2 = q.z - z2, d3 = q.w - z3;
        s += d0*d0; s += d1*d1; s += d2*d2; s += d3*d3;
        if ((c >> 1) == seg) {                 // wave-uniform guard, no divergence
            // out_zq is d_out+1 (4B-aligned) -> dword stores.
            orow[4*c+0] = z0 + d0; orow[4*c+1] = z1 + d1;
            orow[4*c+2] = z2 + d2; orow[4*c+3] = z3 + d3;
        }
    }

    if (seg == 0) {                            // loss + idx: wave 0 only,
        out_idx[blockRow + rrow] = (float)bi;  // identical reduction structure
#pragma unroll                                 // to the verified kernel.
        for (int off = 32; off; off >>= 1) s += __shfl_down(s, off);
        if (tid == 0) atomicAdd(out_loss, s * loss_scale);
    }
}

extern "C" void kernel_launch(void* const* d_in, const int* in_sizes, int n_in,
                              void* d_out, int out_size, void* d_ws, size_t ws_size,
                              hipStream_t stream) {
    const float* z   = (const float*)d_in[0];
    const float* emb = (const float*)d_in[1];
    const int nz = in_sizes[0];          // 4194304
    const int N  = nz / D;               // 65536 rows

    float* out      = (float*)d_out;
    float* out_zq   = out + 1;
    float* out_idx  = out + 1 + (size_t)nz;

    const float loss_scale = 1.25f / (float)nz;

    hipMemsetAsync(out, 0, sizeof(float), stream);  // loss accumulator
    vq_kernel<<<N / ROWS, TPB, 0, stream>>>(z, emb, out, out_zq, out_idx, loss_scale);
}

// Round 4
// 430.947 us; speedup vs baseline: 1.4020x; 1.4020x over previous
//
#include <hip/hip_runtime.h>

// VQ-VAE quantizer: z [16,4096,64] f32, embedding [1024,64] f32.
// Outputs concatenated in d_out (float32): [0]=loss, [1..4194304]=z_q,
// [4194305..]=argmin indices (as float).
//
// Correctness-critical (verified absmax 0.0 previously): argmin mirrors numpy
// bitwise. d = fmaf(-2,dot,(zz+ee)); zz/ee use numpy's pairwise 8-accumulator
// tree with fp-contract OFF; dot uses p0..p3 component accumulators combined
// (p0+p1)+(p2+p3); strict < / tie->smaller-index everywhere == first-index;
// segments merged in ascending order. Loss: wave0 per-row sequential col sum
// + 64-lane shfl tree + one atomic/block (identical to verified kernel).
//
// R5 (resubmitted R3 with pragma-placement compile fix): TRANSPOSED
// parallelization (codes-per-lane). Evidence: R0/R1 (rows-per-lane) stall at
// 38% VALUBusy because the streamed e-row (64 floats = 64 SGPRs) fills the
// ~102-SGPR file -> no double-buffer -> full unordered-SMEM lgkmcnt(0) wait
// (~200cy) per code vs 140cy FMA. R2 proved VMEM broadcast is even worse
// (578us). Fix: each lane PRIVATELY holds 2 e-rows in 128 VGPRs (loaded
// once/block); the shared z-row streams via LDS broadcast ds_read_b128
// (in-order, fine-grained lgkmcnt, pipelined by compiler). Per-row wave
// argmin = in-lane best-of-2 + 6-step shfl_xor butterfly with tie->min-index;
// unroll-2 row loop overlaps butterfly latency with next row's FMAs.

#define D 64
#define NE 1024
#define SEGS 8               // waves per block; wave w owns codes [128w,128w+128)
#define ROWS 64              // rows per block
#define TPB 512

__global__ __launch_bounds__(TPB, 2) void vq_kernel(const float* __restrict__ z,
                                                    const float* __restrict__ emb,
                                                    float* __restrict__ out_loss,
                                                    float* __restrict__ out_zq,
                                                    float* __restrict__ out_idx,
                                                    float loss_scale) {
    __shared__ float lds_z[ROWS * D];      // 16 KB, linear; main-loop reads are
                                           // wave-uniform broadcasts (no conflicts)
    __shared__ float zz_lds[ROWS];
    __shared__ float smv[SEGS * ROWS];
    __shared__ int   smi[SEGS * ROWS];

    const int tid  = threadIdx.x;
    const int lane = tid & 63;
    const int w    = tid >> 6;             // wave id = codebook segment
    const size_t blockRow = (size_t)blockIdx.x * ROWS;

    // --- Stage z tile (64x64) coalesced into LDS (1024 float4s, 2/thread). ---
    {
        const float4* zg4 = (const float4*)(z + blockRow * D);
        float4 v0 = zg4[tid];
        float4 v1 = zg4[tid + TPB];
        ((float4*)lds_z)[tid]       = v0;
        ((float4*)lds_z)[tid + TPB] = v1;
    }

    // --- This lane's two private e-rows -> 128 VGPRs (once per block, L2). ---
    const int jA = (w << 7) + lane;        // w*128 + lane
    const int jB = jA + 64;                // jA < jB: in-lane ascending order
    float4 ea[16], eb[16];
    {
        const float4* e4a = (const float4*)(emb + ((size_t)jA << 6));
        const float4* e4b = (const float4*)(emb + ((size_t)jB << 6));
#pragma unroll
        for (int c = 0; c < 16; ++c) ea[c] = e4a[c];
#pragma unroll
        for (int c = 0; c < 16; ++c) eb[c] = e4b[c];
    }

    // --- ee per code: numpy-pairwise 8-acc tree, contract off (verified order). ---
    float eeA, eeB;
    {
#pragma clang fp contract(off)
        {
            float4 a = ea[0], b = ea[1];
            float r[8];
            r[0]=a.x*a.x; r[1]=a.y*a.y; r[2]=a.z*a.z; r[3]=a.w*a.w;
            r[4]=b.x*b.x; r[5]=b.y*b.y; r[6]=b.z*b.z; r[7]=b.w*b.w;
#pragma unroll
            for (int g = 1; g < 8; ++g) {
                float4 c = ea[2*g], e = ea[2*g+1];
                r[0]=r[0]+c.x*c.x; r[1]=r[1]+c.y*c.y;
                r[2]=r[2]+c.z*c.z; r[3]=r[3]+c.w*c.w;
                r[4]=r[4]+e.x*e.x; r[5]=r[5]+e.y*e.y;
                r[6]=r[6]+e.z*e.z; r[7]=r[7]+e.w*e.w;
            }
            eeA = ((r[0]+r[1])+(r[2]+r[3])) + ((r[4]+r[5])+(r[6]+r[7]));
        }
        {
            float4 a = eb[0], b = eb[1];
            float r[8];
            r[0]=a.x*a.x; r[1]=a.y*a.y; r[2]=a.z*a.z; r[3]=a.w*a.w;
            r[4]=b.x*b.x; r[5]=b.y*b.y; r[6]=b.z*b.z; r[7]=b.w*b.w;
#pragma unroll
            for (int g = 1; g < 8; ++g) {
                float4 c = eb[2*g], e = eb[2*g+1];
                r[0]=r[0]+c.x*c.x; r[1]=r[1]+c.y*c.y;
                r[2]=r[2]+c.z*c.z; r[3]=r[3]+c.w*c.w;
                r[4]=r[4]+e.x*e.x; r[5]=r[5]+e.y*e.y;
                r[6]=r[6]+e.z*e.z; r[7]=r[7]+e.w*e.w;
            }
            eeB = ((r[0]+r[1])+(r[2]+r[3])) + ((r[4]+r[5])+(r[6]+r[7]));
        }
    }

    // --- zz per row (threads 0..63, verified tree), from global (L2-hot). ---
    if (tid < ROWS) {
        float zr[D];
        const float4* zrow4 = (const float4*)(z + (blockRow + tid) * D);
#pragma unroll
        for (int c = 0; c < 16; ++c) {
            float4 v = zrow4[c];
            zr[4*c+0]=v.x; zr[4*c+1]=v.y; zr[4*c+2]=v.z; zr[4*c+3]=v.w;
        }
        {
#pragma clang fp contract(off)
            float r[8];
#pragma unroll
            for (int jj = 0; jj < 8; ++jj) { float t = zr[jj]*zr[jj]; r[jj] = t; }
#pragma unroll
            for (int i = 8; i < 64; i += 8) {
#pragma unroll
                for (int jj = 0; jj < 8; ++jj) { float t = zr[i+jj]*zr[i+jj]; r[jj] = r[jj] + t; }
            }
            zz_lds[tid] = ((r[0]+r[1])+(r[2]+r[3])) + ((r[4]+r[5])+(r[6]+r[7]));
        }
    }
    __syncthreads();   // lds_z + zz_lds ready

    // --- Row loop: z-row broadcast from LDS, 2 codes/lane in registers. ---
#pragma unroll 2
    for (int r = 0; r < ROWS; ++r) {
        const float* zrow = &lds_z[r * D];
        float zzr = zz_lds[r];
        float pa0=0.f, pa1=0.f, pa2=0.f, pa3=0.f;
        float pb0=0.f, pb1=0.f, pb2=0.f, pb3=0.f;
#pragma unroll
        for (int c = 0; c < 16; ++c) {
            float4 zc = *(const float4*)&zrow[c * 4];   // wave-uniform broadcast
            pa0 = fmaf(zc.x, ea[c].x, pa0);
            pa1 = fmaf(zc.y, ea[c].y, pa1);
            pa2 = fmaf(zc.z, ea[c].z, pa2);
            pa3 = fmaf(zc.w, ea[c].w, pa3);
            pb0 = fmaf(zc.x, eb[c].x, pb0);
            pb1 = fmaf(zc.y, eb[c].y, pb1);
            pb2 = fmaf(zc.z, eb[c].z, pb2);
            pb3 = fmaf(zc.w, eb[c].w, pb3);
        }
        float dotA = (pa0 + pa1) + (pa2 + pa3);
        float dotB = (pb0 + pb1) + (pb2 + pb3);
        float t1a = zzr + eeA;                 // mirrors np (zz + ee) rounding
        float t1b = zzr + eeB;
        float dA = fmaf(-2.0f, dotA, t1a);
        float dB = fmaf(-2.0f, dotB, t1b);

        float bv = dA; int bj = jA;            // jA < jB, strict < -> first idx
        if (dB < bv) { bv = dB; bj = jB; }

        // 6-step butterfly min with tie -> smaller index (== global first-index).
#pragma unroll
        for (int off = 32; off; off >>= 1) {
            float ov = __shfl_xor(bv, off);
            int   oi = __shfl_xor(bj, off);
            if (ov < bv || (ov == bv && oi < bj)) { bv = ov; bj = oi; }
        }
        if (lane == 0) { smv[w * ROWS + r] = bv; smi[w * ROWS + r] = bj; }
    }
    __syncthreads();

    // --- Epilogue (verified structure): every wave merges row `lane`
    //     redundantly; wave w stores cols [8w, 8w+8) of z_q. ---
    float zr[D];
    {
        const float4* zrow4 = (const float4*)(z + (blockRow + lane) * D);
#pragma unroll
        for (int c = 0; c < 16; ++c) {
            float4 v = zrow4[c];
            zr[4*c+0]=v.x; zr[4*c+1]=v.y; zr[4*c+2]=v.z; zr[4*c+3]=v.w;
        }
    }
    float best = __builtin_inff();
    int bi = 0;
#pragma unroll
    for (int s = 0; s < SEGS; ++s) {           // ascending seg = ascending j
        float v = smv[s * ROWS + lane];
        if (v < best) { best = v; bi = smi[s * ROWS + lane]; }
    }

    const float4* qe4 = (const float4*)(emb + ((size_t)bi << 6));
    float s = 0.f;
    float* orow = out_zq + (blockRow + lane) * D;
#pragma unroll
    for (int c = 0; c < 16; ++c) {
        float4 q = qe4[c];
        float z0 = zr[4*c+0], z1 = zr[4*c+1], z2 = zr[4*c+2], z3 = zr[4*c+3];
        float d0 = q.x - z0, d1 = q.y - z1, d2 = q.z - z2, d3 = q.w - z3;
        s += d0*d0; s += d1*d1; s += d2*d2; s += d3*d3;
        if ((c >> 1) == w) {                   // wave-uniform guard
            // out_zq is d_out+1 (4B-aligned) -> dword stores.
            orow[4*c+0] = z0 + d0; orow[4*c+1] = z1 + d1;
            orow[4*c+2] = z2 + d2; orow[4*c+3] = z3 + d3;
        }
    }

    if (w == 0) {                              // loss + idx: wave 0 only,
        out_idx[blockRow + lane] = (float)bi;  // identical reduction structure.
#pragma unroll
        for (int off = 32; off; off >>= 1) s += __shfl_down(s, off);
        if (tid == 0) atomicAdd(out_loss, s * loss_scale);
    }
}

extern "C" void kernel_launch(void* const* d_in, const int* in_sizes, int n_in,
                              void* d_out, int out_size, void* d_ws, size_t ws_size,
                              hipStream_t stream) {
    const float* z   = (const float*)d_in[0];
    const float* emb = (const float*)d_in[1];
    const int nz = in_sizes[0];          // 4194304
    const int N  = nz / D;               // 65536 rows

    float* out      = (float*)d_out;
    float* out_zq   = out + 1;
    float* out_idx  = out + 1 + (size_t)nz;

    const float loss_scale = 1.25f / (float)nz;

    hipMemsetAsync(out, 0, sizeof(float), stream);  // loss accumulator
    vq_kernel<<<N / ROWS, TPB, 0, stream>>>(z, emb, out, out_zq, out_idx, loss_scale);
}

// Round 5
// 286.253 us; speedup vs baseline: 2.1106x; 1.5055x over previous
//
#include <hip/hip_runtime.h>

// VQ-VAE quantizer: z [16,4096,64] f32, embedding [1024,64] f32.
// Outputs concatenated in d_out (float32): [0]=loss, [1..4194304]=z_q,
// [4194305..]=argmin indices (as float).
//
// Correctness-critical (verified absmax 0.0 in R0/R1/R2/R4): argmin mirrors
// numpy bitwise. d = fmaf(-2,dot,(zz+ee)); zz/ee use numpy's pairwise
// 8-accumulator tree with fp-contract OFF; dot uses p0..p3 component accums
// combined (p0+p1)+(p2+p3); strict < everywhere -> first-index tie-break;
// segments merged in ascending order. Loss: per-row sequential col sum +
// 64-lane shfl tree + one atomic per 64-row block (identical to verified).
//
// R6 change: TWO-PHASE scan/merge so co-resident waves share one code stream.
// Evidence: R1 (rows-per-lane, scalar e-loads, 8 segments/block) = 208us at
// 38% VALUBusy. Mechanism: each CU hosts waves scanning 8 DIFFERENT 32KB
// segments -> 256KB working set through the ~16KB scalar K$ -> all s_loads
// miss AND the scalar refill path saturates (~26 waves x 256B/code). R2/R4
// proved VMEM-broadcast (578us) and codes-in-VGPR (403us) are worse. Fix:
//  - vq_scan: grid (rowtiles, NSEG) seg-major; all 4 waves of a block (and
//    neighboring blocks) scan the SAME 256-code segment in the same order ->
//    K$ window hits; e-row stays a free SGPR operand in v_fma. Writes
//    per-(row,seg) partial (d-bits, idx) to workspace (2MB).
//  - vq_finish: R1's verified epilogue with the LDS merge replaced by an
//    ascending-segment strict-< merge of the 4 partials (same semantics).

#define D 64
#define NE 1024
#define NSEG 4
#define CPS 256              // codes per segment = NE/NSEG
#define TPB1 256             // 4 waves; each wave = 64 rows, 1 row/lane
#define RPB1 256             // rows per scan block
#define TPB2 512             // finish: 8 waves x 64 rows (R1 epilogue shape)
#define ROWS2 64

__global__ __launch_bounds__(TPB1, 4) void vq_scan(const float* __restrict__ z,
                                                   const float* __restrict__ emb,
                                                   uint2* __restrict__ part,
                                                   int N) {
    __shared__ float ee_lds[CPS];

    const int tid  = threadIdx.x;
    const int lane = tid & 63;
    const int w    = tid >> 6;
    const int seg  = blockIdx.y;
    const int jbase0 = seg * CPS;
    const size_t row = (size_t)blockIdx.x * RPB1 + (size_t)(w << 6) + lane;

    // --- ee for this segment's 256 codes, 1/thread (verified numpy tree). ---
    {
#pragma clang fp contract(off)
        const int j = jbase0 + tid;
        const float4* e4 = (const float4*)(emb + ((size_t)j << 6));
        float4 a = e4[0], b = e4[1];
        float r[8];
        r[0]=a.x*a.x; r[1]=a.y*a.y; r[2]=a.z*a.z; r[3]=a.w*a.w;
        r[4]=b.x*b.x; r[5]=b.y*b.y; r[6]=b.z*b.z; r[7]=b.w*b.w;
#pragma unroll
        for (int g = 1; g < 8; ++g) {
            float4 c = e4[2*g], e = e4[2*g + 1];
            r[0]=r[0]+c.x*c.x; r[1]=r[1]+c.y*c.y;
            r[2]=r[2]+c.z*c.z; r[3]=r[3]+c.w*c.w;
            r[4]=r[4]+e.x*e.x; r[5]=r[5]+e.y*e.y;
            r[6]=r[6]+e.z*e.z; r[7]=r[7]+e.w*e.w;
        }
        ee_lds[tid] = ((r[0]+r[1])+(r[2]+r[3])) + ((r[4]+r[5])+(r[6]+r[7]));
    }

    // --- z row into registers (per-lane row; L1 absorbs the 256B stride). ---
    float zr[D];
    {
        const float4* zrow4 = (const float4*)(z + row * D);
#pragma unroll
        for (int c = 0; c < 16; ++c) {
            float4 v = zrow4[c];
            zr[4*c+0]=v.x; zr[4*c+1]=v.y; zr[4*c+2]=v.z; zr[4*c+3]=v.w;
        }
    }

    // --- zz = numpy-pairwise sum(z*z), contract off (verified tree). ---
    float zz;
    {
#pragma clang fp contract(off)
        float r[8];
#pragma unroll
        for (int jj = 0; jj < 8; ++jj) { float t = zr[jj]*zr[jj]; r[jj] = t; }
#pragma unroll
        for (int i = 8; i < 64; i += 8) {
#pragma unroll
            for (int jj = 0; jj < 8; ++jj) { float t = zr[i+jj]*zr[i+jj]; r[jj] = r[jj] + t; }
        }
        zz = ((r[0]+r[1])+(r[2]+r[3])) + ((r[4]+r[5])+(r[6]+r[7]));
    }
    __syncthreads();   // ee_lds ready

    // --- Scan this block's segment (same stream for all waves on the CU). ---
    float minv = __builtin_inff();
    int mini = 0;
    const int jbase = __builtin_amdgcn_readfirstlane(jbase0);
#pragma unroll 2
    for (int jj = 0; jj < CPS; ++jj) {
        const int j = jbase + jj;
        const float4* ew4 = (const float4*)(emb + ((size_t)j << 6));
        float p0 = 0.f, p1 = 0.f, p2 = 0.f, p3 = 0.f;
#pragma unroll
        for (int c = 0; c < 16; ++c) {
            float4 e4 = ew4[c];
            p0 = fmaf(zr[4*c+0], e4.x, p0);
            p1 = fmaf(zr[4*c+1], e4.y, p1);
            p2 = fmaf(zr[4*c+2], e4.z, p2);
            p3 = fmaf(zr[4*c+3], e4.w, p3);
        }
        float dot = (p0 + p1) + (p2 + p3);
        float t1 = zz + ee_lds[jj];            // mirrors np (zz + ee) rounding
        float d = fmaf(-2.0f, dot, t1);        // == round(t1 - 2*dot)
        if (d < minv) { minv = d; mini = j; }  // strict < -> first index on tie
    }

    // Per-(row, seg) partial: (distance bits, index). Coalesced 8B/lane.
    part[(size_t)seg * (size_t)N + row] = make_uint2(__float_as_uint(minv),
                                                     (unsigned)mini);
}

__global__ __launch_bounds__(TPB2, 4) void vq_finish(const float* __restrict__ z,
                                                     const float* __restrict__ emb,
                                                     const uint2* __restrict__ part,
                                                     float* __restrict__ out_loss,
                                                     float* __restrict__ out_zq,
                                                     float* __restrict__ out_idx,
                                                     float loss_scale, int N) {
    const int tid  = threadIdx.x;
    const int lane = tid & 63;
    const int w    = tid >> 6;
    const size_t blockRow = (size_t)blockIdx.x * ROWS2;
    const size_t row = blockRow + lane;

    // --- Merge the 4 segment partials, ascending seg, strict < (verified
    //     semantics: equals R1's in-block ascending-segment merge). ---
    float best = __builtin_inff();
    int bi = 0;
#pragma unroll
    for (int s = 0; s < NSEG; ++s) {
        uint2 p = part[(size_t)s * (size_t)N + row];
        float v = __uint_as_float(p.x);
        if (v < best) { best = v; bi = (int)p.y; }
    }

    // --- R1's verified epilogue, verbatim: every wave handles row `lane`
    //     redundantly; wave w stores cols [8w, 8w+8) of z_q. ---
    float zr[D];
    {
        const float4* zrow4 = (const float4*)(z + row * D);
#pragma unroll
        for (int c = 0; c < 16; ++c) {
            float4 v = zrow4[c];
            zr[4*c+0]=v.x; zr[4*c+1]=v.y; zr[4*c+2]=v.z; zr[4*c+3]=v.w;
        }
    }

    const float4* qe4 = (const float4*)(emb + ((size_t)bi << 6));
    float s = 0.f;
    float* orow = out_zq + row * D;
#pragma unroll
    for (int c = 0; c < 16; ++c) {
        float4 q = qe4[c];
        float z0 = zr[4*c+0], z1 = zr[4*c+1], z2 = zr[4*c+2], z3 = zr[4*c+3];
        float d0 = q.x - z0, d1 = q.y - z1, d2 = q.z - z2, d3 = q.w - z3;
        s += d0*d0; s += d1*d1; s += d2*d2; s += d3*d3;
        if ((c >> 1) == w) {                   // wave-uniform guard
            // out_zq is d_out+1 (4B-aligned) -> dword stores.
            orow[4*c+0] = z0 + d0; orow[4*c+1] = z1 + d1;
            orow[4*c+2] = z2 + d2; orow[4*c+3] = z3 + d3;
        }
    }

    if (w == 0) {                              // loss + idx: wave 0 only,
        out_idx[row] = (float)bi;              // identical reduction structure.
#pragma unroll
        for (int off = 32; off; off >>= 1) s += __shfl_down(s, off);
        if (tid == 0) atomicAdd(out_loss, s * loss_scale);
    }
}

extern "C" void kernel_launch(void* const* d_in, const int* in_sizes, int n_in,
                              void* d_out, int out_size, void* d_ws, size_t ws_size,
                              hipStream_t stream) {
    const float* z   = (const float*)d_in[0];
    const float* emb = (const float*)d_in[1];
    const int nz = in_sizes[0];          // 4194304
    const int N  = nz / D;               // 65536 rows

    float* out      = (float*)d_out;
    float* out_zq   = out + 1;
    float* out_idx  = out + 1 + (size_t)nz;
    uint2* part     = (uint2*)d_ws;      // NSEG * N * 8B = 2 MB

    const float loss_scale = 1.25f / (float)nz;

    hipMemsetAsync(out, 0, sizeof(float), stream);  // loss accumulator

    dim3 g1(N / RPB1, NSEG);             // x fastest -> seg-major dispatch
    vq_scan<<<g1, TPB1, 0, stream>>>(z, emb, part, N);
    vq_finish<<<N / ROWS2, TPB2, 0, stream>>>(z, emb, part, out, out_zq, out_idx,
                                              loss_scale, N);
}